// Round 1
// baseline (155.734 us; speedup 1.0000x reference)
//
#include <hip/hip_runtime.h>

// NavierStokesLoss: fused jet-propagation (value + 4 first-order + 3 second-order
// tangents = 8 channels/point) through 4->256->256->5 tanh MLP, bf16 MFMA for the
// 256x256 layer, f32 everywhere else.

#define NPTS 65536
#define BP   16               // points per block
#define NBLK (NPTS / BP)      // 4096
#define KPAD 264              // padded k-stride of W2^T (bf16 elems), 528B rows (16B aligned)
#define W3T_OFF 135168        // 256*264*2
#define PART_OFF 143360       // W3T_OFF + 16*256*2

typedef short s16x8 __attribute__((ext_vector_type(8)));
typedef float f32x4 __attribute__((ext_vector_type(4)));

static __device__ __forceinline__ unsigned short f2bf(float f){
  unsigned int u = __float_as_uint(f);
  u = (u + 0x7FFFu + ((u >> 16) & 1u)) >> 16;   // RNE
  return (unsigned short)u;
}
static __device__ __forceinline__ float fast_tanh(float x){
  float e = __expf(2.f * x);
  return 1.f - 2.f / (e + 1.f);
}

// W2 (256x256 f32, [k][j]) -> w2t bf16 [j][KPAD] (transposed, padded)
__global__ void prep_w2t(const float* __restrict__ W2, unsigned short* __restrict__ w2t){
  int k = blockIdx.x, j = threadIdx.x;
  w2t[j * KPAD + k] = f2bf(W2[k * 256 + j]);
}

// W3 (256x5 f32, [k][n]) -> w3t bf16 [16][256] (transposed, rows 5..15 zero)
__global__ void prep_w3t(const float* __restrict__ W3, unsigned short* __restrict__ w3t){
  int idx = blockIdx.x * 256 + threadIdx.x;   // 16 blocks -> 4096
  int n = idx >> 8, k = idx & 255;
  w3t[n * 256 + k] = (n < 5) ? f2bf(W3[k * 5 + n]) : (unsigned short)0;
}

__launch_bounds__(512, 2)
__global__ void ns_main(const float* __restrict__ pts, const float* __restrict__ times,
                        const float* __restrict__ visc,
                        const float* __restrict__ W1, const float* __restrict__ b1,
                        const float* __restrict__ b2, const float* __restrict__ b3,
                        const unsigned short* __restrict__ w2t,
                        const unsigned short* __restrict__ w3t,
                        float* __restrict__ parts){
  // A/B tile: 128 rows (16 pts x 8 channels) x 256 bf16, XOR-swizzled rows (512B)
  __shared__ __align__(16) unsigned char sA[128 * 512];
  __shared__ float sC2[128 * 20];
  __shared__ float pp[16][2];

  const int t   = threadIdx.x;
  const int blk = blockIdx.x;

  // ---------------- layer 1: seed the jet, write bf16 A-tile ----------------
  {
    int p  = t >> 5;            // 16 points
    int jo = (t & 31) << 3;     // 8 consecutive j per thread
    int n  = blk * BP + p;
    float z0 = pts[n*3+0], z1 = pts[n*3+1], z2 = pts[n*3+2], z3 = times[n];
    unsigned short pk[8][8];
    #pragma unroll
    for (int jj = 0; jj < 8; ++jj){
      int j = jo + jj;
      float w0 = W1[j], w1 = W1[256+j], w2 = W1[512+j], w3 = W1[768+j];
      float a  = b1[j] + z0*w0 + z1*w1 + z2*w2 + z3*w3;
      float th = fast_tanh(a);
      float s  = 1.f - th*th;
      float m2 = -2.f * th * s;
      pk[0][jj] = f2bf(th);                     // value
      pk[1][jj] = f2bf(s*w0); pk[2][jj] = f2bf(s*w1);   // d/dx, d/dy
      pk[3][jj] = f2bf(s*w2); pk[4][jj] = f2bf(s*w3);   // d/dz, d/dt
      pk[5][jj] = f2bf(m2*w0*w0);               // d2/dx2
      pk[6][jj] = f2bf(m2*w1*w1);               // d2/dy2
      pk[7][jj] = f2bf(m2*w2*w2);               // d2/dz2
    }
    #pragma unroll
    for (int c = 0; c < 8; ++c){
      int row = (p << 3) + c;
      int off = row*512 + ((jo << 1) ^ ((row & 7) << 4));
      uint4 v;
      v.x = (unsigned)pk[c][0] | ((unsigned)pk[c][1] << 16);
      v.y = (unsigned)pk[c][2] | ((unsigned)pk[c][3] << 16);
      v.z = (unsigned)pk[c][4] | ((unsigned)pk[c][5] << 16);
      v.w = (unsigned)pk[c][6] | ((unsigned)pk[c][7] << 16);
      *(uint4*)(sA + off) = v;
    }
  }
  __syncthreads();

  const int wid = t >> 6, lane = t & 63;
  const int wr = wid >> 2, wc = wid & 3;       // 2x4 wave grid over 128x256 C
  const int g = lane >> 4, r16 = lane & 15;
  const int xorv = (r16 & 7) << 4;             // row&7 == r16&7 for all frag reads

  // ---------------- GEMM2: A(128x256) @ W2(256x256), bf16 MFMA ----------------
  f32x4 acc[4][4];
  #pragma unroll
  for (int a = 0; a < 4; ++a)
    #pragma unroll
    for (int b = 0; b < 4; ++b)
      acc[a][b] = (f32x4){0.f, 0.f, 0.f, 0.f};

  const unsigned char* w2tB = (const unsigned char*)w2t;
  #pragma unroll 2
  for (int k0 = 0; k0 < 256; k0 += 32){
    s16x8 af[4], bfr[4];
    #pragma unroll
    for (int mt = 0; mt < 4; ++mt){
      int row = wr*64 + mt*16 + r16;
      int off = row*512 + ((((k0 << 1)) + (g << 4)) ^ xorv);
      af[mt] = *(const s16x8*)(sA + off);
    }
    #pragma unroll
    for (int nt = 0; nt < 4; ++nt){
      int col = wc*64 + nt*16 + r16;
      bfr[nt] = *(const s16x8*)(w2tB + ((col*KPAD + k0 + g*8) << 1));
    }
    #pragma unroll
    for (int mt = 0; mt < 4; ++mt)
      #pragma unroll
      for (int nt = 0; nt < 4; ++nt)
        acc[mt][nt] = __builtin_amdgcn_mfma_f32_16x16x32_bf16(af[mt], bfr[nt], acc[mt][nt], 0, 0, 0);
  }
  __syncthreads();   // all A-tile reads complete before overwrite

  // ------- recombine (tanh jet through layer-2) + write bf16 B-tile -------
  {
    float b2c[4];
    #pragma unroll
    for (int nt = 0; nt < 4; ++nt) b2c[nt] = b2[wc*64 + nt*16 + r16];
    bool odd = (g & 1);          // odd 4-row group holds channels c4..c7
    #pragma unroll
    for (int mt = 0; mt < 4; ++mt){
      #pragma unroll
      for (int nt = 0; nt < 4; ++nt){
        f32x4 v = acc[mt][nt];
        float o0 = __shfl_xor(v[0], 16, 64);
        float o1 = __shfl_xor(v[1], 16, 64);
        float o2 = __shfl_xor(v[2], 16, 64);
        float o3 = __shfl_xor(v[3], 16, 64);
        float a20 = odd ? o0 : v[0];            // value-channel pre-activation
        float gv  = fast_tanh(a20 + b2c[nt]);
        float s2  = 1.f - gv*gv;
        float r0, r1, r2, r3;
        if (!odd){                               // c0..c3: value, d' x,y,z
          r0 = gv; r1 = s2*v[1]; r2 = s2*v[2]; r3 = s2*v[3];
        } else {                                 // c4: d' t ; c5..7: d'' + chain term
          float t2 = -2.f * gv * s2;
          r0 = s2*v[0];
          r1 = s2*v[1] + t2*o1*o1;
          r2 = s2*v[2] + t2*o2*o2;
          r3 = s2*v[3] + t2*o3*o3;
        }
        int rb   = wr*64 + mt*16 + g*4;
        int colb = (wc*64 + nt*16 + r16) << 1;
        *(unsigned short*)(sA + (rb+0)*512 + (colb ^ (((rb+0)&7) << 4))) = f2bf(r0);
        *(unsigned short*)(sA + (rb+1)*512 + (colb ^ (((rb+1)&7) << 4))) = f2bf(r1);
        *(unsigned short*)(sA + (rb+2)*512 + (colb ^ (((rb+2)&7) << 4))) = f2bf(r2);
        *(unsigned short*)(sA + (rb+3)*512 + (colb ^ (((rb+3)&7) << 4))) = f2bf(r3);
      }
    }
  }
  __syncthreads();

  // ---------------- GEMM3: B(128x256) @ W3pad(256x16) ----------------
  {
    f32x4 acc3 = (f32x4){0.f, 0.f, 0.f, 0.f};
    int rt3 = wid * 16;                         // each wave: one 16-row tile
    const unsigned char* w3tB = (const unsigned char*)w3t;
    #pragma unroll
    for (int k0 = 0; k0 < 256; k0 += 32){
      int row = rt3 + r16;
      int off = row*512 + ((((k0 << 1)) + (g << 4)) ^ xorv);
      s16x8 a3  = *(const s16x8*)(sA + off);
      s16x8 b3f = *(const s16x8*)(w3tB + ((r16*256 + k0 + g*8) << 1));
      acc3 = __builtin_amdgcn_mfma_f32_16x16x32_bf16(a3, b3f, acc3, 0, 0, 0);
    }
    #pragma unroll
    for (int q = 0; q < 4; ++q)
      sC2[(rt3 + g*4 + q)*20 + r16] = acc3[q];
  }
  __syncthreads();

  // ---------------- per-point residual assembly ----------------
  if (t < 16){
    int p = t, n = blk*BP + p;
    float o[8][5];
    #pragma unroll
    for (int c = 0; c < 8; ++c)
      #pragma unroll
      for (int m = 0; m < 5; ++m)
        o[c][m] = sC2[(p*8 + c)*20 + m];
    #pragma unroll
    for (int m = 0; m < 5; ++m) o[0][m] += b3[m];  // bias only on value channel

    float u0 = o[0][0], u1 = o[0][1], u2 = o[0][2];
    float rho = 1000.f * (1.f + 0.1f * fast_tanh(o[0][4]));
    float vis = visc[n];

    // R_i = du_i/dt + u·grad(u_i) + (grad p)_i/rho - nu*lap(u_i) - g_i
    float conv0 = u0*o[1][0] + u1*o[2][0] + u2*o[3][0];
    float conv1 = u0*o[1][1] + u1*o[2][1] + u2*o[3][1];
    float conv2 = u0*o[1][2] + u1*o[2][2] + u2*o[3][2];
    float lap0 = o[5][0] + o[6][0] + o[7][0];
    float lap1 = o[5][1] + o[6][1] + o[7][1];
    float lap2 = o[5][2] + o[6][2] + o[7][2];
    float R0 = o[4][0] + conv0 + o[1][3]/rho - vis*lap0;
    float R1 = o[4][1] + conv1 + o[2][3]/rho - vis*lap1 + 9.81f;
    float R2 = o[4][2] + conv2 + o[3][3]/rho - vis*lap2;
    float Rc = o[1][0] + o[2][1] + o[3][2];

    pp[p][0] = R0*R0 + R1*R1 + R2*R2;
    pp[p][1] = Rc*Rc;
  }
  __syncthreads();
  if (t == 0){
    float sm = 0.f, sc = 0.f;
    #pragma unroll
    for (int i = 0; i < 16; ++i){ sm += pp[i][0]; sc += pp[i][1]; }
    parts[blk*2 + 0] = sm;
    parts[blk*2 + 1] = sc;
  }
}

__global__ void ns_reduce(const float* __restrict__ parts, float* __restrict__ out){
  int t = threadIdx.x;
  float a = 0.f, b = 0.f;
  for (int i = t; i < NBLK; i += 256){ a += parts[2*i]; b += parts[2*i + 1]; }
  #pragma unroll
  for (int off = 32; off; off >>= 1){
    a += __shfl_down(a, off, 64);
    b += __shfl_down(b, off, 64);
  }
  __shared__ float sa[4], sb[4];
  int wid = t >> 6, lane = t & 63;
  if (lane == 0){ sa[wid] = a; sb[wid] = b; }
  __syncthreads();
  if (t == 0){
    float A = sa[0] + sa[1] + sa[2] + sa[3];
    float B = sb[0] + sb[1] + sb[2] + sb[3];
    float mom  = A / (float)NPTS;
    float cont = B / (float)NPTS;
    out[0] = mom + 10.f * cont;
    out[1] = mom;
    out[2] = cont;
  }
}

extern "C" void kernel_launch(void* const* d_in, const int* in_sizes, int n_in,
                              void* d_out, int out_size, void* d_ws, size_t ws_size,
                              hipStream_t stream) {
  const float* pts   = (const float*)d_in[0];
  const float* times = (const float*)d_in[1];
  const float* visc  = (const float*)d_in[2];
  const float* W1    = (const float*)d_in[3];
  const float* b1    = (const float*)d_in[4];
  const float* W2    = (const float*)d_in[5];
  const float* b2    = (const float*)d_in[6];
  const float* W3    = (const float*)d_in[7];
  const float* b3    = (const float*)d_in[8];
  float* out = (float*)d_out;

  unsigned short* w2t = (unsigned short*)d_ws;
  unsigned short* w3t = (unsigned short*)((char*)d_ws + W3T_OFF);
  float* parts        = (float*)((char*)d_ws + PART_OFF);

  prep_w2t<<<256, 256, 0, stream>>>(W2, w2t);
  prep_w3t<<<16, 256, 0, stream>>>(W3, w3t);
  ns_main<<<NBLK, 512, 0, stream>>>(pts, times, visc, W1, b1, b2, b3, w2t, w3t, parts);
  ns_reduce<<<1, 256, 0, stream>>>(parts, out);
}

// Round 2
// 139.520 us; speedup vs baseline: 1.1162x; 1.1162x over previous
//
#include <hip/hip_runtime.h>

// NavierStokesLoss: fused jet-propagation (value + 4 first-order + 3 second-order
// tangents = 8 channels/point) through 4->256->256->5 tanh MLP, bf16 MFMA for the
// 256x256 layer, f32 everywhere else.
// R2: register-local recombination (half-split row layout), cvt_pk bf16 packing,
//     BP=8 / 512-thread blocks for occupancy.

#define NPTS 65536
#define BP   8                // points per block
#define NBLK (NPTS / BP)      // 8192
#define KPAD 264              // padded k-stride of W2^T (bf16 elems)
#define W3T_OFF 135168        // 256*264*2
#define PART_OFF 143360       // W3T_OFF + 16*256*2

typedef short s16x8 __attribute__((ext_vector_type(8)));
typedef float f32x4 __attribute__((ext_vector_type(4)));

static __device__ __forceinline__ unsigned short f2bf(float f){
  unsigned int u = __float_as_uint(f);
  u = (u + 0x7FFFu + ((u >> 16) & 1u)) >> 16;   // RNE
  return (unsigned short)u;
}
static __device__ __forceinline__ unsigned cvtpk_bf16(float lo, float hi){
  unsigned r;
  asm("v_cvt_pk_bf16_f32 %0, %1, %2" : "=v"(r) : "v"(lo), "v"(hi));
  return r;
}
static __device__ __forceinline__ float fast_tanh(float x){
  float e = __expf(2.f * x);
  return 1.f - 2.f / (e + 1.f);
}

// W2 (256x256 f32, [k][j]) -> w2t bf16 [j][KPAD] (transposed, padded)
__global__ void prep_w2t(const float* __restrict__ W2, unsigned short* __restrict__ w2t){
  int k = blockIdx.x, j = threadIdx.x;
  w2t[j * KPAD + k] = f2bf(W2[k * 256 + j]);
}

// W3 (256x5 f32, [k][n]) -> w3t bf16 [16][256] (transposed, rows 5..15 zero)
__global__ void prep_w3t(const float* __restrict__ W3, unsigned short* __restrict__ w3t){
  int idx = blockIdx.x * 256 + threadIdx.x;
  int n = idx >> 8, k = idx & 255;
  w3t[n * 256 + k] = (n < 5) ? f2bf(W3[k * 5 + n]) : (unsigned short)0;
}

__launch_bounds__(512, 6)
__global__ void ns_main(const float* __restrict__ pts, const float* __restrict__ times,
                        const float* __restrict__ visc,
                        const float* __restrict__ W1, const float* __restrict__ b1,
                        const float* __restrict__ b2, const float* __restrict__ b3,
                        const unsigned short* __restrict__ w2t,
                        const unsigned short* __restrict__ w3t,
                        float* __restrict__ parts){
  // A/B tile: 64 rows x 256 bf16, XOR-swizzled (512B rows).
  // Row layout: row = half*32 + p*4 + c  (half0 = channels 0..3, half1 = 4..7)
  __shared__ __align__(16) unsigned char sA[64 * 512];   // 32 KB
  __shared__ float sC2[64 * 20];                          // 5 KB
  __shared__ float pp[8][2];

  const int t   = threadIdx.x;
  const int blk = blockIdx.x;

  // ---------------- layer 1: seed the jet, write bf16 A-tile ----------------
  {
    int p  = t >> 6;            // 8 points, one wave each
    int jo = (t & 63) << 2;     // 4 consecutive j per thread
    int n  = blk * BP + p;
    float z0 = pts[n*3+0], z1 = pts[n*3+1], z2 = pts[n*3+2], z3 = times[n];
    float4 wa = *(const float4*)(W1 + jo);
    float4 wb = *(const float4*)(W1 + 256 + jo);
    float4 wcv = *(const float4*)(W1 + 512 + jo);
    float4 wd = *(const float4*)(W1 + 768 + jo);
    float4 bb = *(const float4*)(b1 + jo);
    float cv[8][4];
    #pragma unroll
    for (int jj = 0; jj < 4; ++jj){
      float w0 = (&wa.x)[jj], w1 = (&wb.x)[jj], w2 = (&wcv.x)[jj], w3 = (&wd.x)[jj];
      float a  = (&bb.x)[jj] + z0*w0 + z1*w1 + z2*w2 + z3*w3;
      float th = fast_tanh(a);
      float s  = 1.f - th*th;
      float m2 = -2.f * th * s;
      cv[0][jj] = th;
      cv[1][jj] = s*w0; cv[2][jj] = s*w1; cv[3][jj] = s*w2; cv[4][jj] = s*w3;
      cv[5][jj] = m2*w0*w0; cv[6][jj] = m2*w1*w1; cv[7][jj] = m2*w2*w2;
    }
    #pragma unroll
    for (int c = 0; c < 8; ++c){
      int row = ((c >= 4) ? 32 : 0) + (p << 2) + (c & 3);
      int off = row*512 + ((jo << 1) ^ ((row & 7) << 4));
      uint2 v;
      v.x = cvtpk_bf16(cv[c][0], cv[c][1]);
      v.y = cvtpk_bf16(cv[c][2], cv[c][3]);
      *(uint2*)(sA + off) = v;
    }
  }
  __syncthreads();

  const int wid = t >> 6, lane = t & 63;
  const int g = lane >> 4, r16 = lane & 15;
  const int xorv = (r16 & 7) << 4;

  // ---------------- GEMM2: A(64x256) @ W2(256x256), bf16 MFMA ----------------
  // 8 waves, each 64 rows x 32 cols; acc[mt][nt], mt 0..3 (rows mt*16), nt 0..1
  f32x4 acc[4][2];
  #pragma unroll
  for (int a = 0; a < 4; ++a)
    #pragma unroll
    for (int b = 0; b < 2; ++b)
      acc[a][b] = (f32x4){0.f, 0.f, 0.f, 0.f};

  const unsigned char* w2tB = (const unsigned char*)w2t;
  int boff0 = ((wid*32 + r16) * KPAD + g*8) << 1;
  int boff1 = ((wid*32 + 16 + r16) * KPAD + g*8) << 1;
  #pragma unroll 2
  for (int k0 = 0; k0 < 256; k0 += 32){
    int colOff = ((k0 << 1) + (g << 4)) ^ xorv;
    s16x8 af[4], bf0, bf1;
    #pragma unroll
    for (int mt = 0; mt < 4; ++mt)
      af[mt] = *(const s16x8*)(sA + (mt*16 + r16)*512 + colOff);
    bf0 = *(const s16x8*)(w2tB + boff0);
    bf1 = *(const s16x8*)(w2tB + boff1);
    boff0 += 64; boff1 += 64;
    #pragma unroll
    for (int mt = 0; mt < 4; ++mt){
      acc[mt][0] = __builtin_amdgcn_mfma_f32_16x16x32_bf16(af[mt], bf0, acc[mt][0], 0, 0, 0);
      acc[mt][1] = __builtin_amdgcn_mfma_f32_16x16x32_bf16(af[mt], bf1, acc[mt][1], 0, 0, 0);
    }
  }
  __syncthreads();   // all A-tile reads complete before overwrite

  // ------- recombine (tanh jet through layer-2), fully register-local -------
  {
    float b2c0 = b2[wid*32 + r16];
    float b2c1 = b2[wid*32 + 16 + r16];
    #pragma unroll
    for (int mt = 0; mt < 2; ++mt){
      #pragma unroll
      for (int nt = 0; nt < 2; ++nt){
        f32x4 v = acc[mt][nt];       // channels 0..3: value, dx, dy, dz
        f32x4 w = acc[mt+2][nt];     // channels 4..7: dt, dxx, dyy, dzz
        float gv = fast_tanh(v[0] + (nt ? b2c1 : b2c0));
        float s2 = 1.f - gv*gv;
        float t2 = -2.f * gv * s2;
        float r0 = gv,      r1 = s2*v[1], r2 = s2*v[2], r3 = s2*v[3];
        float r4 = s2*w[0];
        float r5 = fmaf(t2*v[1], v[1], s2*w[1]);
        float r6 = fmaf(t2*v[2], v[2], s2*w[2]);
        float r7 = fmaf(t2*v[3], v[3], s2*w[3]);
        int colb = (wid*32 + nt*16 + r16) << 1;
        int rh0 = mt*16 + g*4;
        int rh1 = 32 + mt*16 + g*4;
        unsigned u;
        u = cvtpk_bf16(r0, r1);
        *(unsigned short*)(sA + (rh0+0)*512 + (colb ^ (((rh0+0)&7) << 4))) = (unsigned short)u;
        *(unsigned short*)(sA + (rh0+1)*512 + (colb ^ (((rh0+1)&7) << 4))) = (unsigned short)(u >> 16);
        u = cvtpk_bf16(r2, r3);
        *(unsigned short*)(sA + (rh0+2)*512 + (colb ^ (((rh0+2)&7) << 4))) = (unsigned short)u;
        *(unsigned short*)(sA + (rh0+3)*512 + (colb ^ (((rh0+3)&7) << 4))) = (unsigned short)(u >> 16);
        u = cvtpk_bf16(r4, r5);
        *(unsigned short*)(sA + (rh1+0)*512 + (colb ^ (((rh1+0)&7) << 4))) = (unsigned short)u;
        *(unsigned short*)(sA + (rh1+1)*512 + (colb ^ (((rh1+1)&7) << 4))) = (unsigned short)(u >> 16);
        u = cvtpk_bf16(r6, r7);
        *(unsigned short*)(sA + (rh1+2)*512 + (colb ^ (((rh1+2)&7) << 4))) = (unsigned short)u;
        *(unsigned short*)(sA + (rh1+3)*512 + (colb ^ (((rh1+3)&7) << 4))) = (unsigned short)(u >> 16);
      }
    }
  }
  __syncthreads();

  // ---------------- GEMM3: B(64x256) @ W3pad(256x16) ----------------
  if (wid < 4){
    f32x4 acc3 = (f32x4){0.f, 0.f, 0.f, 0.f};
    int rt3 = wid * 16;
    const unsigned char* w3tB = (const unsigned char*)w3t;
    #pragma unroll
    for (int k0 = 0; k0 < 256; k0 += 32){
      int colOff = ((k0 << 1) + (g << 4)) ^ xorv;
      s16x8 a3  = *(const s16x8*)(sA + (rt3 + r16)*512 + colOff);
      s16x8 b3f = *(const s16x8*)(w3tB + ((r16*256 + k0 + g*8) << 1));
      acc3 = __builtin_amdgcn_mfma_f32_16x16x32_bf16(a3, b3f, acc3, 0, 0, 0);
    }
    #pragma unroll
    for (int q = 0; q < 4; ++q)
      sC2[(rt3 + g*4 + q)*20 + r16] = acc3[q];
  }
  __syncthreads();

  // ---------------- per-point residual assembly ----------------
  if (t < 8){
    int p = t, n = blk*BP + p;
    float o[8][5];
    #pragma unroll
    for (int c = 0; c < 8; ++c){
      int row = ((c >= 4) ? 32 : 0) + (p << 2) + (c & 3);
      #pragma unroll
      for (int m = 0; m < 5; ++m)
        o[c][m] = sC2[row*20 + m];
    }
    #pragma unroll
    for (int m = 0; m < 5; ++m) o[0][m] += b3[m];  // bias only on value channel

    float u0 = o[0][0], u1 = o[0][1], u2 = o[0][2];
    float rho = 1000.f * (1.f + 0.1f * fast_tanh(o[0][4]));
    float vis = visc[n];

    float conv0 = u0*o[1][0] + u1*o[2][0] + u2*o[3][0];
    float conv1 = u0*o[1][1] + u1*o[2][1] + u2*o[3][1];
    float conv2 = u0*o[1][2] + u1*o[2][2] + u2*o[3][2];
    float lap0 = o[5][0] + o[6][0] + o[7][0];
    float lap1 = o[5][1] + o[6][1] + o[7][1];
    float lap2 = o[5][2] + o[6][2] + o[7][2];
    float R0 = o[4][0] + conv0 + o[1][3]/rho - vis*lap0;
    float R1 = o[4][1] + conv1 + o[2][3]/rho - vis*lap1 + 9.81f;
    float R2 = o[4][2] + conv2 + o[3][3]/rho - vis*lap2;
    float Rc = o[1][0] + o[2][1] + o[3][2];

    pp[p][0] = R0*R0 + R1*R1 + R2*R2;
    pp[p][1] = Rc*Rc;
  }
  __syncthreads();
  if (t == 0){
    float sm = 0.f, sc = 0.f;
    #pragma unroll
    for (int i = 0; i < 8; ++i){ sm += pp[i][0]; sc += pp[i][1]; }
    parts[blk*2 + 0] = sm;
    parts[blk*2 + 1] = sc;
  }
}

__global__ void ns_reduce(const float* __restrict__ parts, float* __restrict__ out){
  int t = threadIdx.x;
  float a = 0.f, b = 0.f;
  for (int i = t; i < NBLK; i += 256){ a += parts[2*i]; b += parts[2*i + 1]; }
  #pragma unroll
  for (int off = 32; off; off >>= 1){
    a += __shfl_down(a, off, 64);
    b += __shfl_down(b, off, 64);
  }
  __shared__ float sa[4], sb[4];
  int wid = t >> 6, lane = t & 63;
  if (lane == 0){ sa[wid] = a; sb[wid] = b; }
  __syncthreads();
  if (t == 0){
    float A = sa[0] + sa[1] + sa[2] + sa[3];
    float B = sb[0] + sb[1] + sb[2] + sb[3];
    float mom  = A / (float)NPTS;
    float cont = B / (float)NPTS;
    out[0] = mom + 10.f * cont;
    out[1] = mom;
    out[2] = cont;
  }
}

extern "C" void kernel_launch(void* const* d_in, const int* in_sizes, int n_in,
                              void* d_out, int out_size, void* d_ws, size_t ws_size,
                              hipStream_t stream) {
  const float* pts   = (const float*)d_in[0];
  const float* times = (const float*)d_in[1];
  const float* visc  = (const float*)d_in[2];
  const float* W1    = (const float*)d_in[3];
  const float* b1    = (const float*)d_in[4];
  const float* W2    = (const float*)d_in[5];
  const float* b2    = (const float*)d_in[6];
  const float* W3    = (const float*)d_in[7];
  const float* b3    = (const float*)d_in[8];
  float* out = (float*)d_out;

  unsigned short* w2t = (unsigned short*)d_ws;
  unsigned short* w3t = (unsigned short*)((char*)d_ws + W3T_OFF);
  float* parts        = (float*)((char*)d_ws + PART_OFF);

  prep_w2t<<<256, 256, 0, stream>>>(W2, w2t);
  prep_w3t<<<16, 256, 0, stream>>>(W3, w3t);
  ns_main<<<NBLK, 512, 0, stream>>>(pts, times, visc, W1, b1, b2, b3, w2t, w3t, parts);
  ns_reduce<<<1, 256, 0, stream>>>(parts, out);
}

// Round 3
// 135.632 us; speedup vs baseline: 1.1482x; 1.0287x over previous
//
#include <hip/hip_runtime.h>

// NavierStokesLoss: fused jet-propagation (value + 4 first-order + 3 second-order
// tangents = 8 channels/point) through 4->256->256->5 tanh MLP, bf16 MFMA for the
// 256x256 layer, f32 everywhere else.
// R3: BP=16 (M=128, 2x4 wave grid of 64x64 tiles -> A-reads/pt halved),
//     immediate-offset recombine writes, GEMM3 on all 8 waves with in-place
//     writeback into own sA rows (no sC2), shfl tail, fast tanh via exp2+rcp.

#define NPTS 65536
#define BP   16
#define NBLK (NPTS / BP)      // 4096
#define KPAD 264              // padded k-stride of W2^T (bf16 elems); 528B = 33*16B
#define W3T_OFF 135168        // 256*264*2
#define PART_OFF 143360       // W3T_OFF + 16*256*2

typedef short s16x8 __attribute__((ext_vector_type(8)));
typedef float f32x4 __attribute__((ext_vector_type(4)));

static __device__ __forceinline__ unsigned short f2bf(float f){
  unsigned int u = __float_as_uint(f);
  u = (u + 0x7FFFu + ((u >> 16) & 1u)) >> 16;   // RNE
  return (unsigned short)u;
}
static __device__ __forceinline__ unsigned cvtpk_bf16(float lo, float hi){
  unsigned r;
  asm("v_cvt_pk_bf16_f32 %0, %1, %2" : "=v"(r) : "v"(lo), "v"(hi));
  return r;
}
static __device__ __forceinline__ float fast_tanh(float x){
  float e = exp2f(x * 2.8853900817779268f);     // exp(2x)
  return 1.f - 2.f * __builtin_amdgcn_rcpf(e + 1.f);
}

// W2 (256x256 f32, [k][j]) -> w2t bf16 [j][KPAD] (transposed, padded)
__global__ void prep_w2t(const float* __restrict__ W2, unsigned short* __restrict__ w2t){
  int k = blockIdx.x, j = threadIdx.x;
  w2t[j * KPAD + k] = f2bf(W2[k * 256 + j]);
}

// W3 (256x5 f32, [k][n]) -> w3t bf16 [16][256] (transposed, rows 5..15 zero)
__global__ void prep_w3t(const float* __restrict__ W3, unsigned short* __restrict__ w3t){
  int idx = blockIdx.x * 256 + threadIdx.x;
  int n = idx >> 8, k = idx & 255;
  w3t[n * 256 + k] = (n < 5) ? f2bf(W3[k * 5 + n]) : (unsigned short)0;
}

// Row layout of the 128x256 jet tile:
//   row(p,c) = (p&8)*8 + (c&4)*8 + (p&7)*4 + (c&3)
// so points 0-7 / 8-15 split across wr, channel halves 0-3 / 4-7 split at +32,
// and each MFMA C-lane holds all 4 channels of one half of one point.
__launch_bounds__(512, 4)
__global__ void ns_main(const float* __restrict__ pts, const float* __restrict__ times,
                        const float* __restrict__ visc,
                        const float* __restrict__ W1, const float* __restrict__ b1,
                        const float* __restrict__ b2, const float* __restrict__ b3,
                        const unsigned short* __restrict__ w2t,
                        const unsigned short* __restrict__ w3t,
                        float* __restrict__ parts){
  __shared__ __align__(16) unsigned char sA[128 * 512];   // 64 KiB exactly

  const int t   = threadIdx.x;
  const int blk = blockIdx.x;

  // ---------------- layer 1: seed the jet, write bf16 A-tile ----------------
  {
    int p  = t >> 5;            // 16 points, 32 threads each
    int jo = (t & 31) << 3;     // 8 consecutive j per thread
    int n  = blk * BP + p;
    float z0 = pts[n*3+0], z1 = pts[n*3+1], z2 = pts[n*3+2], z3 = times[n];
    float w0v[8], w1v[8], w2v[8], w3v[8], bv[8];
    *(float4*)(w0v)   = *(const float4*)(W1 + jo);
    *(float4*)(w0v+4) = *(const float4*)(W1 + jo + 4);
    *(float4*)(w1v)   = *(const float4*)(W1 + 256 + jo);
    *(float4*)(w1v+4) = *(const float4*)(W1 + 256 + jo + 4);
    *(float4*)(w2v)   = *(const float4*)(W1 + 512 + jo);
    *(float4*)(w2v+4) = *(const float4*)(W1 + 512 + jo + 4);
    *(float4*)(w3v)   = *(const float4*)(W1 + 768 + jo);
    *(float4*)(w3v+4) = *(const float4*)(W1 + 768 + jo + 4);
    *(float4*)(bv)    = *(const float4*)(b1 + jo);
    *(float4*)(bv+4)  = *(const float4*)(b1 + jo + 4);
    float cv[8][8];
    #pragma unroll
    for (int jj = 0; jj < 8; ++jj){
      float w0 = w0v[jj], w1 = w1v[jj], w2 = w2v[jj], w3 = w3v[jj];
      float a  = bv[jj] + z0*w0 + z1*w1 + z2*w2 + z3*w3;
      float th = fast_tanh(a);
      float s  = 1.f - th*th;
      float m2 = -2.f * th * s;
      cv[0][jj] = th;
      cv[1][jj] = s*w0; cv[2][jj] = s*w1; cv[3][jj] = s*w2; cv[4][jj] = s*w3;
      cv[5][jj] = m2*w0*w0; cv[6][jj] = m2*w1*w1; cv[7][jj] = m2*w2*w2;
    }
    #pragma unroll
    for (int c = 0; c < 8; ++c){
      int row = ((p & 8) << 3) + ((c & 4) << 3) + ((p & 7) << 2) + (c & 3);
      int off = row*512 + ((jo << 1) ^ ((row & 7) << 4));
      uint4 v;
      v.x = cvtpk_bf16(cv[c][0], cv[c][1]);
      v.y = cvtpk_bf16(cv[c][2], cv[c][3]);
      v.z = cvtpk_bf16(cv[c][4], cv[c][5]);
      v.w = cvtpk_bf16(cv[c][6], cv[c][7]);
      *(uint4*)(sA + off) = v;
    }
  }
  __syncthreads();

  const int wid = t >> 6, lane = t & 63;
  const int g = lane >> 4, r16 = lane & 15;
  const int wr = wid >> 2, wc = wid & 3;       // 2x4 wave grid over 128x256 C
  const int xorv = (r16 & 7) << 4;

  // ---------------- GEMM2: A(128x256) @ W2(256x256), bf16 MFMA ----------------
  // wave tile 64x64: acc[mt][nt], rows wr*64+mt*16, cols wc*64+nt*16
  f32x4 acc[4][4];
  #pragma unroll
  for (int a = 0; a < 4; ++a)
    #pragma unroll
    for (int b = 0; b < 4; ++b)
      acc[a][b] = (f32x4){0.f, 0.f, 0.f, 0.f};

  {
    const unsigned char* w2tB = (const unsigned char*)w2t;
    int abase0 = (wr*64 + r16)*512;
    const unsigned char* bptr[4];
    #pragma unroll
    for (int nt = 0; nt < 4; ++nt)
      bptr[nt] = w2tB + (((wc*64 + nt*16 + r16)*KPAD + g*8) << 1);
    #pragma unroll
    for (int ks = 0; ks < 8; ++ks){
      int k0 = ks * 32;
      int X  = ((k0 << 1) + (g << 4)) ^ xorv;
      s16x8 af[4], bfr[4];
      #pragma unroll
      for (int mt = 0; mt < 4; ++mt)
        af[mt] = *(const s16x8*)(sA + abase0 + mt*8192 + X);
      #pragma unroll
      for (int nt = 0; nt < 4; ++nt)
        bfr[nt] = *(const s16x8*)(bptr[nt] + (k0 << 1));
      #pragma unroll
      for (int mt = 0; mt < 4; ++mt)
        #pragma unroll
        for (int nt = 0; nt < 4; ++nt)
          acc[mt][nt] = __builtin_amdgcn_mfma_f32_16x16x32_bf16(af[mt], bfr[nt], acc[mt][nt], 0, 0, 0);
    }
  }
  __syncthreads();   // all A-tile reads complete before overwrite

  // ------- recombine (tanh jet through layer-2), register-local, imm-offset writes -------
  {
    float b2c[4];
    #pragma unroll
    for (int nt = 0; nt < 4; ++nt) b2c[nt] = b2[wc*64 + nt*16 + r16];
    // write addresses: row = wr*64 + (c&4)*8 + 16*mt + 4*g + c3 ; row&7 = 4*(g&1)+c3
    int wadr[4][4];   // [nt][c3] for mt=0, channel<4; +8192*mt, +16384 for c+4
    #pragma unroll
    for (int nt = 0; nt < 4; ++nt){
      int colb = (wc*64 + nt*16 + r16) << 1;
      #pragma unroll
      for (int c3 = 0; c3 < 4; ++c3)
        wadr[nt][c3] = (wr*64 + g*4 + c3)*512 + (colb ^ ((((g & 1) << 2) + c3) << 4));
    }
    #pragma unroll
    for (int mt = 0; mt < 2; ++mt){
      #pragma unroll
      for (int nt = 0; nt < 4; ++nt){
        f32x4 v = acc[mt][nt];       // channels 0..3: value, dx, dy, dz
        f32x4 w = acc[mt+2][nt];     // channels 4..7: dt, dxx, dyy, dzz
        float gv = fast_tanh(v[0] + b2c[nt]);
        float s2 = 1.f - gv*gv;
        float t2 = -2.f * gv * s2;
        float r0 = gv,      r1 = s2*v[1], r2 = s2*v[2], r3 = s2*v[3];
        float r4 = s2*w[0];
        float r5 = fmaf(t2*v[1], v[1], s2*w[1]);
        float r6 = fmaf(t2*v[2], v[2], s2*w[2]);
        float r7 = fmaf(t2*v[3], v[3], s2*w[3]);
        unsigned u;
        u = cvtpk_bf16(r0, r4);
        *(unsigned short*)(sA + wadr[nt][0] + mt*8192)         = (unsigned short)u;
        *(unsigned short*)(sA + wadr[nt][0] + mt*8192 + 16384) = (unsigned short)(u >> 16);
        u = cvtpk_bf16(r1, r5);
        *(unsigned short*)(sA + wadr[nt][1] + mt*8192)         = (unsigned short)u;
        *(unsigned short*)(sA + wadr[nt][1] + mt*8192 + 16384) = (unsigned short)(u >> 16);
        u = cvtpk_bf16(r2, r6);
        *(unsigned short*)(sA + wadr[nt][2] + mt*8192)         = (unsigned short)u;
        *(unsigned short*)(sA + wadr[nt][2] + mt*8192 + 16384) = (unsigned short)(u >> 16);
        u = cvtpk_bf16(r3, r7);
        *(unsigned short*)(sA + wadr[nt][3] + mt*8192)         = (unsigned short)u;
        *(unsigned short*)(sA + wadr[nt][3] + mt*8192 + 16384) = (unsigned short)(u >> 16);
      }
    }
  }
  __syncthreads();

  // ---------------- GEMM3: B(128x256) @ W3pad(256x16), all 8 waves ----------------
  {
    f32x4 acc3 = (f32x4){0.f, 0.f, 0.f, 0.f};
    int rbase = (wid*16 + r16)*512;
    const unsigned char* w3tB = (const unsigned char*)w3t + ((r16*256 + g*8) << 1);
    #pragma unroll
    for (int ks = 0; ks < 8; ++ks){
      int k0 = ks * 32;
      int X  = ((k0 << 1) + (g << 4)) ^ xorv;
      s16x8 a3  = *(const s16x8*)(sA + rbase + X);
      s16x8 b3f = *(const s16x8*)(w3tB + (k0 << 1));
      acc3 = __builtin_amdgcn_mfma_f32_16x16x32_bf16(a3, b3f, acc3, 0, 0, 0);
    }
    // write the 5 useful outputs back into the first bytes of this wave's own rows
    if (r16 < 5){
      #pragma unroll
      for (int q = 0; q < 4; ++q){
        int row = wid*16 + g*4 + q;
        *(float*)(sA + row*512 + ((r16 << 2) ^ ((row & 7) << 4))) = acc3[q];
      }
    }
  }
  __syncthreads();

  // ---------------- per-point residual assembly (wave 0) ----------------
  float m_part = 0.f, c_part = 0.f;
  if (t < 16){
    int p = t, n = blk*BP + p;
    float o[8][5];
    #pragma unroll
    for (int c = 0; c < 8; ++c){
      int row = ((p & 8) << 3) + ((c & 4) << 3) + ((p & 7) << 2) + (c & 3);
      int swz = (row & 7) << 4;
      f32x4 v4 = *(const f32x4*)(sA + row*512 + swz);
      o[c][0] = v4[0]; o[c][1] = v4[1]; o[c][2] = v4[2]; o[c][3] = v4[3];
      o[c][4] = *(const float*)(sA + row*512 + (16 ^ swz));
    }
    #pragma unroll
    for (int m = 0; m < 5; ++m) o[0][m] += b3[m];  // bias only on value channel

    float u0 = o[0][0], u1 = o[0][1], u2 = o[0][2];
    float rho = 1000.f * (1.f + 0.1f * fast_tanh(o[0][4]));
    float rr  = __builtin_amdgcn_rcpf(rho);
    float vis = visc[n];

    float conv0 = u0*o[1][0] + u1*o[2][0] + u2*o[3][0];
    float conv1 = u0*o[1][1] + u1*o[2][1] + u2*o[3][1];
    float conv2 = u0*o[1][2] + u1*o[2][2] + u2*o[3][2];
    float lap0 = o[5][0] + o[6][0] + o[7][0];
    float lap1 = o[5][1] + o[6][1] + o[7][1];
    float lap2 = o[5][2] + o[6][2] + o[7][2];
    float R0 = o[4][0] + conv0 + o[1][3]*rr - vis*lap0;
    float R1 = o[4][1] + conv1 + o[2][3]*rr - vis*lap1 + 9.81f;
    float R2 = o[4][2] + conv2 + o[3][3]*rr - vis*lap2;
    float Rc = o[1][0] + o[2][1] + o[3][2];

    m_part = R0*R0 + R1*R1 + R2*R2;
    c_part = Rc*Rc;
  }
  if (t < 64){
    #pragma unroll
    for (int off = 1; off < 16; off <<= 1){
      m_part += __shfl_xor(m_part, off, 64);
      c_part += __shfl_xor(c_part, off, 64);
    }
    if (t == 0){
      float2 pr; pr.x = m_part; pr.y = c_part;
      *(float2*)(parts + blk*2) = pr;
    }
  }
}

__global__ void ns_reduce(const float* __restrict__ parts, float* __restrict__ out){
  int t = threadIdx.x;
  float a = 0.f, b = 0.f;
  for (int i = t; i < NBLK; i += 256){ a += parts[2*i]; b += parts[2*i + 1]; }
  #pragma unroll
  for (int off = 32; off; off >>= 1){
    a += __shfl_down(a, off, 64);
    b += __shfl_down(b, off, 64);
  }
  __shared__ float sa[4], sb[4];
  int wid = t >> 6, lane = t & 63;
  if (lane == 0){ sa[wid] = a; sb[wid] = b; }
  __syncthreads();
  if (t == 0){
    float A = sa[0] + sa[1] + sa[2] + sa[3];
    float B = sb[0] + sb[1] + sb[2] + sb[3];
    float mom  = A / (float)NPTS;
    float cont = B / (float)NPTS;
    out[0] = mom + 10.f * cont;
    out[1] = mom;
    out[2] = cont;
  }
}

extern "C" void kernel_launch(void* const* d_in, const int* in_sizes, int n_in,
                              void* d_out, int out_size, void* d_ws, size_t ws_size,
                              hipStream_t stream) {
  const float* pts   = (const float*)d_in[0];
  const float* times = (const float*)d_in[1];
  const float* visc  = (const float*)d_in[2];
  const float* W1    = (const float*)d_in[3];
  const float* b1    = (const float*)d_in[4];
  const float* W2    = (const float*)d_in[5];
  const float* b2    = (const float*)d_in[6];
  const float* W3    = (const float*)d_in[7];
  const float* b3    = (const float*)d_in[8];
  float* out = (float*)d_out;

  unsigned short* w2t = (unsigned short*)d_ws;
  unsigned short* w3t = (unsigned short*)((char*)d_ws + W3T_OFF);
  float* parts        = (float*)((char*)d_ws + PART_OFF);

  prep_w2t<<<256, 256, 0, stream>>>(W2, w2t);
  prep_w3t<<<16, 256, 0, stream>>>(W3, w3t);
  ns_main<<<NBLK, 512, 0, stream>>>(pts, times, visc, W1, b1, b2, b3, w2t, w3t, parts);
  ns_reduce<<<1, 256, 0, stream>>>(parts, out);
}